// Round 1
// baseline (310.829 us; speedup 1.0000x reference)
//
#include <hip/hip_runtime.h>

// Problem constants
constexpr int Bn = 16, Cd = 256, Hn = 64, Wn = 64, Kc = 1024;
constexpr int QUANT_ELEMS = Bn * Hn * Wn * Cd;   // 16777216
constexpr int LOSS_OFF = QUANT_ELEMS;            // +0 codebook_loss, +1 commitment_loss
constexpr int IDX_OFF = QUANT_ELEMS + 2;         // 65536 indices (stored as float)

typedef _Float16 half8 __attribute__((ext_vector_type(8)));
typedef float f32x4 __attribute__((ext_vector_type(4)));

// ws layout (bytes):
constexpr size_t WS_CBFH = 0;                    // 512 KB fp16 hi codebook (B-frag)
constexpr size_t WS_CBFL = 512 * 1024;           // 512 KB fp16 lo residual
constexpr size_t WS_C2   = 1024 * 1024;          // 4 KB
constexpr size_t WS_CBT  = 1024 * 1024 + 8192;   // 1 MB cbT (C,K) fp32

// ---------------------------------------------------------------------------
// Prep v5: 64 blocks x 16 codes (was 16 blocks x 64 -> 4x more CUs busy).
// Produces cbT (C,K), cbFh/cbFl (B-fragment fp16 hi/lo), c2, zeroes losses.
__global__ __launch_bounds__(256) void prep(const float* __restrict__ cb,
                                            float* __restrict__ cbT,
                                            _Float16* __restrict__ cbFh,
                                            _Float16* __restrict__ cbFl,
                                            float* __restrict__ c2,
                                            float* __restrict__ out) {
    __shared__ float cbs[16][257];   // 16 codes x 256 c, +1 pad
    const int tid = threadIdx.x;
    const int k0 = blockIdx.x * 16;  // 64 blocks
    {   // load tile, coalesced along c
        const int c4 = (tid & 63) * 4;
        const int r0 = tid >> 6;
        #pragma unroll
        for (int it = 0; it < 4; ++it) {
            const int r = r0 + it * 4;
            const float4 v = *(const float4*)&cb[(size_t)(k0 + r) * Cd + c4];
            cbs[r][c4] = v.x; cbs[r][c4 + 1] = v.y; cbs[r][c4 + 2] = v.z; cbs[r][c4 + 3] = v.w;
        }
    }
    __syncthreads();
    {   // cbT: 16 consecutive k per store row
        const int kk = tid & 15, j0 = tid >> 4;
        for (int j = j0; j < 256; j += 16)
            cbT[(size_t)j * Kc + k0 + kk] = cbs[kk][j];
    }
    {   // c2: 16 threads per code
        const int i = tid >> 4, part = tid & 15;
        float s = 0.f;
        #pragma unroll
        for (int c = part * 16; c < part * 16 + 16; ++c) { const float v = cbs[i][c]; s += v * v; }
        s += __shfl_xor(s, 1);
        s += __shfl_xor(s, 2);
        s += __shfl_xor(s, 4);
        s += __shfl_xor(s, 8);
        if (part == 0) c2[k0 + i] = s;
    }
    // fragments: this block's 16 codes == exactly one n-tile (ntile = blockIdx.x).
    // B frag (16x16x32 f16): lane l holds B[k=(l>>4)*8+j][n=l&15]
    for (int t = tid; t < 512; t += 256) {
        const int kblk = t >> 6;     // 0..7
        const int l = t & 63;
        const int code_l = l & 15;
        const int cbase = kblk * 32 + (l >> 4) * 8;
        half8 hv, lv;
        #pragma unroll
        for (int j = 0; j < 8; ++j) {
            const float v = cbs[code_l][cbase + j];
            const _Float16 hh = (_Float16)v;
            hv[j] = hh;
            lv[j] = (_Float16)(v - (float)hh);
        }
        const size_t e = (size_t)(blockIdx.x * 8 + kblk) * 64 + l;
        *(half8*)(cbFh + e * 8) = hv;
        *(half8*)(cbFl + e * 8) = lv;
    }
    if (blockIdx.x == 0 && tid == 0) {
        out[LOSS_OFF] = 0.f; out[LOSS_OFF + 1] = 0.f;
    }
}

// ---------------------------------------------------------------------------
// Main MFMA kernel v5. Block = one (b,h) = 64 rows x 256 c.
// Changes vs v4:
//  - Axl dropped from LDS (it was never an MFMA operand: terms are xh*ch +
//    xh*cl = xh*c). LDS 69 KB -> ~36.5 KB -> 4 blocks/CU (occupancy 2x).
//  - Epilogue re-reads exact x from global (coalesced, L3-resident) for loss.
//  - Fixup FUSED: flagged rows (gap < 0.12, ~9 sigma of dropped xl*c term)
//    are exactly rescanned in-block via cbT before the epilogue, so quant
//    gather + idx write + loss all use the corrected index. No 3rd kernel.
__global__ __launch_bounds__(256, 4) void vq_main(const float* __restrict__ x,
                                                  const _Float16* __restrict__ cbFh,
                                                  const _Float16* __restrict__ cbFl,
                                                  const float* __restrict__ c2,
                                                  const float* __restrict__ cb,
                                                  const float* __restrict__ cbT,
                                                  float* __restrict__ out) {
    __shared__ half8 Axh[2048];   // 32 KB: [kblk 8][mt 4][lane 64]; reused as rescan scratch
    __shared__ float q1ds[4][64];
    __shared__ int   q1is[4][64];
    __shared__ float q2ds[4][64];
    __shared__ int   idx_s[64];
    __shared__ float red[4];
    __shared__ int   flg[64];
    __shared__ int   nflag;

    // rescan scratch overlays Axh (only used after the K-loop is done with it)
    float* xs  = (float*)Axh;          // 256 floats
    float* dsm = xs + 256;             // 256 floats
    int*   kkm = (int*)(dsm + 256);    // 256 ints

    const int tid = threadIdx.x;
    const int lane = tid & 63;
    const int wv = tid >> 6;
    const int bh = blockIdx.x;
    const int b = bh >> 6, h = bh & 63;

    if (tid == 0) nflag = 0;

    // ---- Stage x-tile once: gather + fp16 hi + lane-contiguous b128 writes
    {
        const int m = tid & 15;           // row within m-tile
        const int q = (tid >> 4) & 3;     // k-quad
        const int mt = tid >> 6;          // m-tile
        const int w = mt * 16 + m;
        const float* xb = x + ((size_t)b * Cd * Hn + h) * Wn + w;   // + c*4096
        #pragma unroll
        for (int kblk = 0; kblk < 8; ++kblk) {
            half8 hv;
            #pragma unroll
            for (int j = 0; j < 8; ++j) {
                const int c = kblk * 32 + q * 8 + j;
                const float v = xb[(size_t)c * (Hn * Wn)];
                hv[j] = (_Float16)v;
            }
            Axh[(kblk * 4 + mt) * 64 + (q * 16 + m)] = hv;   // == ...*64 + lane
        }
    }
    __syncthreads();

    float q1d[16], q2d[16];
    int   q1i[16];
    #pragma unroll
    for (int i = 0; i < 16; ++i) { q1d[i] = 3.4e38f; q2d[i] = 3.4e38f; q1i[i] = 0; }

    #pragma unroll 1
    for (int grp = 0; grp < 4; ++grp) {
        f32x4 acc[4][4];   // [mt][nt]
        #pragma unroll
        for (int mt = 0; mt < 4; ++mt)
            #pragma unroll
            for (int nt = 0; nt < 4; ++nt) acc[mt][nt] = (f32x4){0.f, 0.f, 0.f, 0.f};

        #pragma unroll 2
        for (int kblk = 0; kblk < 8; ++kblk) {
            half8 bhf[4], blf[4];
            #pragma unroll
            for (int nt = 0; nt < 4; ++nt) {
                const int ntile = wv * 16 + grp * 4 + nt;
                const size_t be = ((size_t)(ntile * 8 + kblk) * 64 + lane) * 8;
                bhf[nt] = *(const half8*)(cbFh + be);
                blf[nt] = *(const half8*)(cbFl + be);
            }
            half8 ahf[4];
            #pragma unroll
            for (int mt = 0; mt < 4; ++mt)
                ahf[mt] = Axh[(kblk * 4 + mt) * 64 + lane];
            // 2 terms: xh*ch + xh*cl = xh*c
            #pragma unroll
            for (int nt = 0; nt < 4; ++nt)
                #pragma unroll
                for (int mt = 0; mt < 4; ++mt)
                    acc[mt][nt] = __builtin_amdgcn_mfma_f32_16x16x32_f16(ahf[mt], bhf[nt], acc[mt][nt], 0, 0, 0);
            #pragma unroll
            for (int nt = 0; nt < 4; ++nt)
                #pragma unroll
                for (int mt = 0; mt < 4; ++mt)
                    acc[mt][nt] = __builtin_amdgcn_mfma_f32_16x16x32_f16(ahf[mt], blf[nt], acc[mt][nt], 0, 0, 0);
        }

        // fold this group's 64 codes into per-row top-2 (no tie-break)
        #pragma unroll
        for (int nt = 0; nt < 4; ++nt) {
            const int code = (wv * 16 + grp * 4 + nt) * 16 + (lane & 15);
            const float c2v = c2[code];
            #pragma unroll
            for (int mt = 0; mt < 4; ++mt) {
                #pragma unroll
                for (int reg = 0; reg < 4; ++reg) {
                    const float d = fmaf(-2.f, acc[mt][nt][reg], c2v);
                    const int qi = mt * 4 + reg;
                    const bool better = d < q1d[qi];
                    const float second = better ? q1d[qi] : d;
                    q2d[qi] = fminf(q2d[qi], second);
                    q1i[qi] = better ? code : q1i[qi];
                    q1d[qi] = fminf(q1d[qi], d);
                }
            }
        }
    }

    // cross-lane top-2 reduce over the 16 code-columns (lane&15)
    #pragma unroll
    for (int off = 1; off < 16; off <<= 1) {
        #pragma unroll
        for (int qi = 0; qi < 16; ++qi) {
            const float od1 = __shfl_xor(q1d[qi], off);
            const int   oi1 = __shfl_xor(q1i[qi], off);
            const float od2 = __shfl_xor(q2d[qi], off);
            const bool obetter = od1 < q1d[qi];
            const float loser = obetter ? q1d[qi] : od1;
            q2d[qi] = fminf(fminf(q2d[qi], od2), loser);
            q1d[qi] = obetter ? od1 : q1d[qi];
            q1i[qi] = obetter ? oi1 : q1i[qi];
        }
    }
    if ((lane & 15) == 0) {
        #pragma unroll
        for (int qi = 0; qi < 16; ++qi) {
            const int mt = qi >> 2, reg = qi & 3;
            const int row = mt * 16 + (lane >> 4) * 4 + reg;
            q1ds[wv][row] = q1d[qi];
            q1is[wv][row] = q1i[qi];
            q2ds[wv][row] = q2d[qi];
        }
    }
    __syncthreads();
    if (tid < 64) {
        float d1 = q1ds[0][tid]; int i1 = q1is[0][tid]; float d2 = q2ds[0][tid];
        #pragma unroll
        for (int v = 1; v < 4; ++v) {
            const float od1 = q1ds[v][tid]; const int oi1 = q1is[v][tid]; const float od2 = q2ds[v][tid];
            const bool obetter = od1 < d1;
            const float loser = obetter ? d1 : od1;
            d2 = fminf(fminf(d2, od2), loser);
            d1 = obetter ? od1 : d1;
            i1 = obetter ? oi1 : i1;
        }
        idx_s[tid] = i1;
        if (d2 - d1 < 0.12f) {               // tight gap -> exact in-block rescore
            const int pos = atomicAdd(&nflag, 1);
            flg[pos] = tid;
        }
    }
    __syncthreads();

    // ---- Fused exact rescan of flagged rows (replaces fixup kernel).
    // Ties => gap 0 => flagged, and the rescan tie-break (lowest k) matches
    // JAX argmin-first semantics.
    const int nf = nflag;
    for (int fi = 0; fi < nf; ++fi) {
        const int wrow = flg[fi];
        xs[tid] = x[(((size_t)b * Cd + tid) * Hn + h) * Wn + wrow];
        __syncthreads();
        float dot[4] = {0.f, 0.f, 0.f, 0.f};
        #pragma unroll 8
        for (int c = 0; c < Cd; ++c) {
            const float4 v = ((const float4*)(cbT + (size_t)c * Kc))[tid];
            const float xc = xs[c];
            dot[0] = fmaf(v.x, xc, dot[0]);
            dot[1] = fmaf(v.y, xc, dot[1]);
            dot[2] = fmaf(v.z, xc, dot[2]);
            dot[3] = fmaf(v.w, xc, dot[3]);
        }
        float bd = 3.4e38f; int bk = 0;
        #pragma unroll
        for (int j = 0; j < 4; ++j) {
            const int k = tid * 4 + j;
            const float d = c2[k] - 2.f * dot[j];
            if (d < bd) { bd = d; bk = k; }
        }
        dsm[tid] = bd; kkm[tid] = bk;
        __syncthreads();
        for (int s = 128; s > 0; s >>= 1) {
            if (tid < s) {
                const float od = dsm[tid + s]; const int ok = kkm[tid + s];
                if (od < dsm[tid] || (od == dsm[tid] && ok < kkm[tid])) { dsm[tid] = od; kkm[tid] = ok; }
            }
            __syncthreads();
        }
        if (tid == 0) idx_s[wrow] = kkm[0];
        __syncthreads();
    }

    // indices out (post-rescan, exact)
    if (tid < 64) out[IDX_OFF + bh * 64 + tid] = (float)idx_s[tid];

    // ---- Fused epilogue: quant gather (L2-resident cb), coalesced writes,
    //      loss from EXACT re-read x (256B coalesced segments, L3-resident).
    {
        const int w = tid & 63;           // row
        const int cq = wv;                // c-quarter: c in [cq*64, cq*64+64)
        const int myidx = idx_s[w];
        const float4* cbrow = (const float4*)(cb + (size_t)myidx * Cd + cq * 64);
        const float* xrow = x + (((size_t)b * Cd + cq * 64) * Hn + h) * Wn + w;  // + c_local*4096
        float* orow = out + (((size_t)b * Cd + cq * 64) * Hn + h) * Wn + w;
        float lsum = 0.f;
        #pragma unroll
        for (int i = 0; i < 16; ++i) {    // 16 float4 = 64 c
            const float4 qv4 = cbrow[i];
            const size_t c0 = (size_t)(i * 4) * (Hn * Wn);
            const float xv0 = xrow[c0];
            const float xv1 = xrow[c0 + 1 * (Hn * Wn)];
            const float xv2 = xrow[c0 + 2 * (Hn * Wn)];
            const float xv3 = xrow[c0 + 3 * (Hn * Wn)];
            const float d0 = qv4.x - xv0, d1 = qv4.y - xv1, d2 = qv4.z - xv2, d3 = qv4.w - xv3;
            lsum += d0 * d0 + d1 * d1 + d2 * d2 + d3 * d3;
            orow[c0] = qv4.x;
            orow[c0 + 1 * (Hn * Wn)] = qv4.y;
            orow[c0 + 2 * (Hn * Wn)] = qv4.z;
            orow[c0 + 3 * (Hn * Wn)] = qv4.w;
        }
        #pragma unroll
        for (int off = 32; off >= 1; off >>= 1) lsum += __shfl_xor(lsum, off);
        if (lane == 0) red[wv] = lsum;
    }
    __syncthreads();
    if (tid == 0) {
        const float s = (red[0] + red[1] + red[2] + red[3]) * (1.0f / 16777216.0f);
        atomicAdd(out + LOSS_OFF, s);
        atomicAdd(out + LOSS_OFF + 1, s);
    }
}

// ---------------------------------------------------------------------------
extern "C" void kernel_launch(void* const* d_in, const int* in_sizes, int n_in,
                              void* d_out, int out_size, void* d_ws, size_t ws_size,
                              hipStream_t stream) {
    const float* x  = (const float*)d_in[0];   // (16,256,64,64)
    const float* cb = (const float*)d_in[1];   // (1024,256)
    float* out = (float*)d_out;
    char* ws = (char*)d_ws;
    _Float16* cbFh = (_Float16*)(ws + WS_CBFH);
    _Float16* cbFl = (_Float16*)(ws + WS_CBFL);
    float* c2      = (float*)(ws + WS_C2);
    float* cbT     = (float*)(ws + WS_CBT);

    prep<<<64, 256, 0, stream>>>(cb, cbT, cbFh, cbFl, c2, out);
    vq_main<<<Bn * Hn, 256, 0, stream>>>(x, cbFh, cbFl, c2, cb, cbT, out);
}

// Round 2
// 255.951 us; speedup vs baseline: 1.2144x; 1.2144x over previous
//
#include <hip/hip_runtime.h>

// Problem constants
constexpr int Bn = 16, Cd = 256, Hn = 64, Wn = 64, Kc = 1024;
constexpr int QUANT_ELEMS = Bn * Hn * Wn * Cd;   // 16777216
constexpr int LOSS_OFF = QUANT_ELEMS;            // +0 codebook_loss, +1 commitment_loss
constexpr int IDX_OFF = QUANT_ELEMS + 2;         // 65536 indices (stored as float)

typedef _Float16 half8 __attribute__((ext_vector_type(8)));
typedef float f32x4 __attribute__((ext_vector_type(4)));

// ws layout (bytes):
constexpr size_t WS_CBFH = 0;                    // 512 KB fp16 hi codebook (B-frag)
constexpr size_t WS_CBFL = 512 * 1024;           // 512 KB fp16 lo residual
constexpr size_t WS_C2   = 1024 * 1024;          // 4 KB
constexpr size_t WS_CBT  = 1024 * 1024 + 8192;   // 1 MB cbT (C,K) fp32

// ---------------------------------------------------------------------------
// Prep: 64 blocks x 16 codes. Produces cbT (C,K), cbFh/cbFl (B-fragment fp16
// hi/lo), c2, zeroes losses.
__global__ __launch_bounds__(256) void prep(const float* __restrict__ cb,
                                            float* __restrict__ cbT,
                                            _Float16* __restrict__ cbFh,
                                            _Float16* __restrict__ cbFl,
                                            float* __restrict__ c2,
                                            float* __restrict__ out) {
    __shared__ float cbs[16][257];   // 16 codes x 256 c, +1 pad
    const int tid = threadIdx.x;
    const int k0 = blockIdx.x * 16;  // 64 blocks
    {   // load tile, coalesced along c
        const int c4 = (tid & 63) * 4;
        const int r0 = tid >> 6;
        #pragma unroll
        for (int it = 0; it < 4; ++it) {
            const int r = r0 + it * 4;
            const float4 v = *(const float4*)&cb[(size_t)(k0 + r) * Cd + c4];
            cbs[r][c4] = v.x; cbs[r][c4 + 1] = v.y; cbs[r][c4 + 2] = v.z; cbs[r][c4 + 3] = v.w;
        }
    }
    __syncthreads();
    {   // cbT: 16 consecutive k per store row
        const int kk = tid & 15, j0 = tid >> 4;
        for (int j = j0; j < 256; j += 16)
            cbT[(size_t)j * Kc + k0 + kk] = cbs[kk][j];
    }
    {   // c2: 16 threads per code
        const int i = tid >> 4, part = tid & 15;
        float s = 0.f;
        #pragma unroll
        for (int c = part * 16; c < part * 16 + 16; ++c) { const float v = cbs[i][c]; s += v * v; }
        s += __shfl_xor(s, 1);
        s += __shfl_xor(s, 2);
        s += __shfl_xor(s, 4);
        s += __shfl_xor(s, 8);
        if (part == 0) c2[k0 + i] = s;
    }
    // fragments: this block's 16 codes == exactly one n-tile (ntile = blockIdx.x).
    // B frag (16x16x32 f16): lane l holds B[k=(l>>4)*8+j][n=l&15]
    for (int t = tid; t < 512; t += 256) {
        const int kblk = t >> 6;     // 0..7
        const int l = t & 63;
        const int code_l = l & 15;
        const int cbase = kblk * 32 + (l >> 4) * 8;
        half8 hv, lv;
        #pragma unroll
        for (int j = 0; j < 8; ++j) {
            const float v = cbs[code_l][cbase + j];
            const _Float16 hh = (_Float16)v;
            hv[j] = hh;
            lv[j] = (_Float16)(v - (float)hh);
        }
        const size_t e = (size_t)(blockIdx.x * 8 + kblk) * 64 + l;
        *(half8*)(cbFh + e * 8) = hv;
        *(half8*)(cbFl + e * 8) = lv;
    }
    if (blockIdx.x == 0 && tid == 0) {
        out[LOSS_OFF] = 0.f; out[LOSS_OFF + 1] = 0.f;
    }
}

// ---------------------------------------------------------------------------
// Main MFMA kernel v6. Block = one (b,h) = 64 rows x 256 c.
// Changes vs v5 (which spilled: VGPR cap 128 < ~170 live -> 210 MB scratch):
//  - acc tile narrowed to [4 mt][2 nt] (32 VGPRs, was 64); top-2 fold every
//    2 n-tiles (8 groups). Live set ~140 regs.
//  - __launch_bounds__(256, 3): cap ~170 unified regs -> no spill, 3 blk/CU.
// Retained from v5: Axh-only LDS (32 KB), fused exact rescan of tight-gap
// rows, epilogue loss from exact re-read x.
__global__ __launch_bounds__(256, 3) void vq_main(const float* __restrict__ x,
                                                  const _Float16* __restrict__ cbFh,
                                                  const _Float16* __restrict__ cbFl,
                                                  const float* __restrict__ c2,
                                                  const float* __restrict__ cb,
                                                  const float* __restrict__ cbT,
                                                  float* __restrict__ out) {
    __shared__ half8 Axh[2048];   // 32 KB: [kblk 8][mt 4][lane 64]; reused as rescan scratch
    __shared__ float q1ds[4][64];
    __shared__ int   q1is[4][64];
    __shared__ float q2ds[4][64];
    __shared__ int   idx_s[64];
    __shared__ float red[4];
    __shared__ int   flg[64];
    __shared__ int   nflag;

    // rescan scratch overlays Axh (only used after the K-loop is done with it)
    float* xs  = (float*)Axh;          // 256 floats
    float* dsm = xs + 256;             // 256 floats
    int*   kkm = (int*)(dsm + 256);    // 256 ints

    const int tid = threadIdx.x;
    const int lane = tid & 63;
    const int wv = tid >> 6;
    const int bh = blockIdx.x;
    const int b = bh >> 6, h = bh & 63;

    if (tid == 0) nflag = 0;

    // ---- Stage x-tile once: gather + fp16 hi + lane-contiguous b128 writes
    {
        const int m = tid & 15;           // row within m-tile
        const int q = (tid >> 4) & 3;     // k-quad
        const int mt = tid >> 6;          // m-tile
        const int w = mt * 16 + m;
        const float* xb = x + ((size_t)b * Cd * Hn + h) * Wn + w;   // + c*4096
        #pragma unroll
        for (int kblk = 0; kblk < 8; ++kblk) {
            half8 hv;
            #pragma unroll
            for (int j = 0; j < 8; ++j) {
                const int c = kblk * 32 + q * 8 + j;
                const float v = xb[(size_t)c * (Hn * Wn)];
                hv[j] = (_Float16)v;
            }
            Axh[(kblk * 4 + mt) * 64 + (q * 16 + m)] = hv;   // == ...*64 + lane
        }
    }
    __syncthreads();

    float q1d[16], q2d[16];
    int   q1i[16];
    #pragma unroll
    for (int i = 0; i < 16; ++i) { q1d[i] = 3.4e38f; q2d[i] = 3.4e38f; q1i[i] = 0; }

    #pragma unroll 1
    for (int grp = 0; grp < 8; ++grp) {   // 2 n-tiles per group
        f32x4 acc[4][2];   // [mt][nt]
        #pragma unroll
        for (int mt = 0; mt < 4; ++mt)
            #pragma unroll
            for (int nt = 0; nt < 2; ++nt) acc[mt][nt] = (f32x4){0.f, 0.f, 0.f, 0.f};

        #pragma unroll 2
        for (int kblk = 0; kblk < 8; ++kblk) {
            half8 bhf[2], blf[2];
            #pragma unroll
            for (int nt = 0; nt < 2; ++nt) {
                const int ntile = wv * 16 + grp * 2 + nt;
                const size_t be = ((size_t)(ntile * 8 + kblk) * 64 + lane) * 8;
                bhf[nt] = *(const half8*)(cbFh + be);
                blf[nt] = *(const half8*)(cbFl + be);
            }
            half8 ahf[4];
            #pragma unroll
            for (int mt = 0; mt < 4; ++mt)
                ahf[mt] = Axh[(kblk * 4 + mt) * 64 + lane];
            // 2 terms: xh*ch + xh*cl = xh*c
            #pragma unroll
            for (int nt = 0; nt < 2; ++nt)
                #pragma unroll
                for (int mt = 0; mt < 4; ++mt)
                    acc[mt][nt] = __builtin_amdgcn_mfma_f32_16x16x32_f16(ahf[mt], bhf[nt], acc[mt][nt], 0, 0, 0);
            #pragma unroll
            for (int nt = 0; nt < 2; ++nt)
                #pragma unroll
                for (int mt = 0; mt < 4; ++mt)
                    acc[mt][nt] = __builtin_amdgcn_mfma_f32_16x16x32_f16(ahf[mt], blf[nt], acc[mt][nt], 0, 0, 0);
        }

        // fold this group's 32 codes into per-row top-2 (no tie-break)
        #pragma unroll
        for (int nt = 0; nt < 2; ++nt) {
            const int code = (wv * 16 + grp * 2 + nt) * 16 + (lane & 15);
            const float c2v = c2[code];
            #pragma unroll
            for (int mt = 0; mt < 4; ++mt) {
                #pragma unroll
                for (int reg = 0; reg < 4; ++reg) {
                    const float d = fmaf(-2.f, acc[mt][nt][reg], c2v);
                    const int qi = mt * 4 + reg;
                    const bool better = d < q1d[qi];
                    const float second = better ? q1d[qi] : d;
                    q2d[qi] = fminf(q2d[qi], second);
                    q1i[qi] = better ? code : q1i[qi];
                    q1d[qi] = fminf(q1d[qi], d);
                }
            }
        }
    }

    // cross-lane top-2 reduce over the 16 code-columns (lane&15)
    #pragma unroll
    for (int off = 1; off < 16; off <<= 1) {
        #pragma unroll
        for (int qi = 0; qi < 16; ++qi) {
            const float od1 = __shfl_xor(q1d[qi], off);
            const int   oi1 = __shfl_xor(q1i[qi], off);
            const float od2 = __shfl_xor(q2d[qi], off);
            const bool obetter = od1 < q1d[qi];
            const float loser = obetter ? q1d[qi] : od1;
            q2d[qi] = fminf(fminf(q2d[qi], od2), loser);
            q1d[qi] = obetter ? od1 : q1d[qi];
            q1i[qi] = obetter ? oi1 : q1i[qi];
        }
    }
    if ((lane & 15) == 0) {
        #pragma unroll
        for (int qi = 0; qi < 16; ++qi) {
            const int mt = qi >> 2, reg = qi & 3;
            const int row = mt * 16 + (lane >> 4) * 4 + reg;
            q1ds[wv][row] = q1d[qi];
            q1is[wv][row] = q1i[qi];
            q2ds[wv][row] = q2d[qi];
        }
    }
    __syncthreads();
    if (tid < 64) {
        float d1 = q1ds[0][tid]; int i1 = q1is[0][tid]; float d2 = q2ds[0][tid];
        #pragma unroll
        for (int v = 1; v < 4; ++v) {
            const float od1 = q1ds[v][tid]; const int oi1 = q1is[v][tid]; const float od2 = q2ds[v][tid];
            const bool obetter = od1 < d1;
            const float loser = obetter ? d1 : od1;
            d2 = fminf(fminf(d2, od2), loser);
            d1 = obetter ? od1 : d1;
            i1 = obetter ? oi1 : i1;
        }
        idx_s[tid] = i1;
        if (d2 - d1 < 0.12f) {               // tight gap -> exact in-block rescore
            const int pos = atomicAdd(&nflag, 1);
            flg[pos] = tid;
        }
    }
    __syncthreads();

    // ---- Fused exact rescan of flagged rows (replaces fixup kernel).
    // Ties => gap 0 => flagged, and the rescan tie-break (lowest k) matches
    // JAX argmin-first semantics.
    const int nf = nflag;
    for (int fi = 0; fi < nf; ++fi) {
        const int wrow = flg[fi];
        xs[tid] = x[(((size_t)b * Cd + tid) * Hn + h) * Wn + wrow];
        __syncthreads();
        float dot[4] = {0.f, 0.f, 0.f, 0.f};
        #pragma unroll 8
        for (int c = 0; c < Cd; ++c) {
            const float4 v = ((const float4*)(cbT + (size_t)c * Kc))[tid];
            const float xc = xs[c];
            dot[0] = fmaf(v.x, xc, dot[0]);
            dot[1] = fmaf(v.y, xc, dot[1]);
            dot[2] = fmaf(v.z, xc, dot[2]);
            dot[3] = fmaf(v.w, xc, dot[3]);
        }
        float bd = 3.4e38f; int bk = 0;
        #pragma unroll
        for (int j = 0; j < 4; ++j) {
            const int k = tid * 4 + j;
            const float d = c2[k] - 2.f * dot[j];
            if (d < bd) { bd = d; bk = k; }
        }
        dsm[tid] = bd; kkm[tid] = bk;
        __syncthreads();
        for (int s = 128; s > 0; s >>= 1) {
            if (tid < s) {
                const float od = dsm[tid + s]; const int ok = kkm[tid + s];
                if (od < dsm[tid] || (od == dsm[tid] && ok < kkm[tid])) { dsm[tid] = od; kkm[tid] = ok; }
            }
            __syncthreads();
        }
        if (tid == 0) idx_s[wrow] = kkm[0];
        __syncthreads();
    }

    // indices out (post-rescan, exact)
    if (tid < 64) out[IDX_OFF + bh * 64 + tid] = (float)idx_s[tid];

    // ---- Fused epilogue: quant gather (L2-resident cb), coalesced writes,
    //      loss from EXACT re-read x (256B coalesced segments, L3-resident).
    {
        const int w = tid & 63;           // row
        const int cq = wv;                // c-quarter: c in [cq*64, cq*64+64)
        const int myidx = idx_s[w];
        const float4* cbrow = (const float4*)(cb + (size_t)myidx * Cd + cq * 64);
        const float* xrow = x + (((size_t)b * Cd + cq * 64) * Hn + h) * Wn + w;  // + c_local*4096
        float* orow = out + (((size_t)b * Cd + cq * 64) * Hn + h) * Wn + w;
        float lsum = 0.f;
        #pragma unroll
        for (int i = 0; i < 16; ++i) {    // 16 float4 = 64 c
            const float4 qv4 = cbrow[i];
            const size_t c0 = (size_t)(i * 4) * (Hn * Wn);
            const float xv0 = xrow[c0];
            const float xv1 = xrow[c0 + 1 * (Hn * Wn)];
            const float xv2 = xrow[c0 + 2 * (Hn * Wn)];
            const float xv3 = xrow[c0 + 3 * (Hn * Wn)];
            const float d0 = qv4.x - xv0, d1 = qv4.y - xv1, d2 = qv4.z - xv2, d3 = qv4.w - xv3;
            lsum += d0 * d0 + d1 * d1 + d2 * d2 + d3 * d3;
            orow[c0] = qv4.x;
            orow[c0 + 1 * (Hn * Wn)] = qv4.y;
            orow[c0 + 2 * (Hn * Wn)] = qv4.z;
            orow[c0 + 3 * (Hn * Wn)] = qv4.w;
        }
        #pragma unroll
        for (int off = 32; off >= 1; off >>= 1) lsum += __shfl_xor(lsum, off);
        if (lane == 0) red[wv] = lsum;
    }
    __syncthreads();
    if (tid == 0) {
        const float s = (red[0] + red[1] + red[2] + red[3]) * (1.0f / 16777216.0f);
        atomicAdd(out + LOSS_OFF, s);
        atomicAdd(out + LOSS_OFF + 1, s);
    }
}

// ---------------------------------------------------------------------------
extern "C" void kernel_launch(void* const* d_in, const int* in_sizes, int n_in,
                              void* d_out, int out_size, void* d_ws, size_t ws_size,
                              hipStream_t stream) {
    const float* x  = (const float*)d_in[0];   // (16,256,64,64)
    const float* cb = (const float*)d_in[1];   // (1024,256)
    float* out = (float*)d_out;
    char* ws = (char*)d_ws;
    _Float16* cbFh = (_Float16*)(ws + WS_CBFH);
    _Float16* cbFl = (_Float16*)(ws + WS_CBFL);
    float* c2      = (float*)(ws + WS_C2);
    float* cbT     = (float*)(ws + WS_CBT);

    prep<<<64, 256, 0, stream>>>(cb, cbT, cbFh, cbFl, c2, out);
    vq_main<<<Bn * Hn, 256, 0, stream>>>(x, cbFh, cbFl, c2, cb, cbT, out);
}

// Round 3
// 242.142 us; speedup vs baseline: 1.2837x; 1.0570x over previous
//
#include <hip/hip_runtime.h>

// Problem constants
constexpr int Bn = 16, Cd = 256, Hn = 64, Wn = 64, Kc = 1024;
constexpr int QUANT_ELEMS = Bn * Hn * Wn * Cd;   // 16777216
constexpr int LOSS_OFF = QUANT_ELEMS;            // +0 codebook_loss, +1 commitment_loss
constexpr int IDX_OFF = QUANT_ELEMS + 2;         // 65536 indices (stored as float)

typedef _Float16 half8 __attribute__((ext_vector_type(8)));
typedef float f32x4 __attribute__((ext_vector_type(4)));

// ws layout (bytes):
constexpr size_t WS_CBFH = 0;                    // 512 KB fp16 hi codebook (B-frag)
constexpr size_t WS_CBFL = 512 * 1024;           // 512 KB fp16 lo residual
constexpr size_t WS_C2   = 1024 * 1024;          // 4 KB

// Gap threshold for exact top-2 rescore. 3-term error (dropped xl*cl +
// fp32-accum noise) sigma ~1e-5 -> 1e-4 ~ 10 sigma. Expected flags: ~10
// rows across the whole grid, each costing ~400 cyc.
constexpr float THR = 1e-4f;

// ---------------------------------------------------------------------------
// Prep: 64 blocks x 16 codes. Produces cbFh/cbFl (B-fragment fp16 hi/lo), c2,
// zeroes losses. cbT/fixup machinery dropped (3-term main needs no full scans).
__global__ __launch_bounds__(256) void prep(const float* __restrict__ cb,
                                            _Float16* __restrict__ cbFh,
                                            _Float16* __restrict__ cbFl,
                                            float* __restrict__ c2,
                                            float* __restrict__ out) {
    __shared__ float cbs[16][257];   // 16 codes x 256 c, +1 pad
    const int tid = threadIdx.x;
    const int k0 = blockIdx.x * 16;  // 64 blocks
    {   // load tile, coalesced along c
        const int c4 = (tid & 63) * 4;
        const int r0 = tid >> 6;
        #pragma unroll
        for (int it = 0; it < 4; ++it) {
            const int r = r0 + it * 4;
            const float4 v = *(const float4*)&cb[(size_t)(k0 + r) * Cd + c4];
            cbs[r][c4] = v.x; cbs[r][c4 + 1] = v.y; cbs[r][c4 + 2] = v.z; cbs[r][c4 + 3] = v.w;
        }
    }
    __syncthreads();
    {   // c2: 16 threads per code
        const int i = tid >> 4, part = tid & 15;
        float s = 0.f;
        #pragma unroll
        for (int c = part * 16; c < part * 16 + 16; ++c) { const float v = cbs[i][c]; s += v * v; }
        s += __shfl_xor(s, 1);
        s += __shfl_xor(s, 2);
        s += __shfl_xor(s, 4);
        s += __shfl_xor(s, 8);
        if (part == 0) c2[k0 + i] = s;
    }
    // fragments: this block's 16 codes == exactly one n-tile (ntile = blockIdx.x).
    // B frag (16x16x32 f16): lane l holds B[k=(l>>4)*8+j][n=l&15]
    for (int t = tid; t < 512; t += 256) {
        const int kblk = t >> 6;     // 0..7
        const int l = t & 63;
        const int code_l = l & 15;
        const int cbase = kblk * 32 + (l >> 4) * 8;
        half8 hv, lv;
        #pragma unroll
        for (int j = 0; j < 8; ++j) {
            const float v = cbs[code_l][cbase + j];
            const _Float16 hh = (_Float16)v;
            hv[j] = hh;
            lv[j] = (_Float16)(v - (float)hh);
        }
        const size_t e = (size_t)(blockIdx.x * 8 + kblk) * 64 + l;
        *(half8*)(cbFh + e * 8) = hv;
        *(half8*)(cbFl + e * 8) = lv;
    }
    if (blockIdx.x == 0 && tid == 0) {
        out[LOSS_OFF] = 0.f; out[LOSS_OFF + 1] = 0.f;
    }
}

// ---------------------------------------------------------------------------
// Main MFMA kernel v7. Block = one (b,h) = 64 rows x 256 c.
// Changes vs v6 (182 us, MfmaUtil 15.6, rescans ~30-40 us + stragglers):
//  - THREE MFMA terms: xh*ch + xh*cl + xl*ch (drop only xl*cl). Approx error
//    sigma ~1e-5 -> thr 1e-4 -> ~10 flagged rows GLOBALLY, each fixed by a
//    cheap exact top-2 rescore (no cbT, no 1MB scans, no straggler blocks).
//  - Axl back in LDS (70 KB total -> 2 blocks/CU); explicit 1-deep B-frag
//    prefetch pipelines the L2 loads under the 24-MFMA burst.
//  - Epilogue/loss from LDS-exact x (xh+xl, err 2^-24) - no global re-read.
__global__ __launch_bounds__(256, 2) void vq_main(const float* __restrict__ x,
                                                  const _Float16* __restrict__ cbFh,
                                                  const _Float16* __restrict__ cbFl,
                                                  const float* __restrict__ c2,
                                                  const float* __restrict__ cb,
                                                  float* __restrict__ out) {
    __shared__ half8 Axh[2048];   // 32 KB: [kblk 8][mt 4][lane 64]
    __shared__ half8 Axl[2048];   // 32 KB
    __shared__ float q1ds[4][64];
    __shared__ int   q1is[4][64];
    __shared__ float q2ds[4][64];
    __shared__ int   q2is[4][64];
    __shared__ int   idx_s[64];
    __shared__ float red[4];
    __shared__ int   flg[64];     // packed: row | (i2 << 6)
    __shared__ int   nflag;

    const int tid = threadIdx.x;
    const int lane = tid & 63;
    const int wv = tid >> 6;
    const int bh = blockIdx.x;
    const int b = bh >> 6, h = bh & 63;

    if (tid == 0) nflag = 0;

    // ---- Stage x-tile once: gather + fp16 hi/lo split + lane-contiguous writes
    {
        const int m = tid & 15;           // row within m-tile
        const int q = (tid >> 4) & 3;     // k-quad
        const int mt = tid >> 6;          // m-tile
        const int w = mt * 16 + m;
        const float* xb = x + ((size_t)b * Cd * Hn + h) * Wn + w;   // + c*4096
        #pragma unroll
        for (int kblk = 0; kblk < 8; ++kblk) {
            half8 hv, lv;
            #pragma unroll
            for (int j = 0; j < 8; ++j) {
                const int c = kblk * 32 + q * 8 + j;
                const float v = xb[(size_t)c * (Hn * Wn)];
                const _Float16 hh = (_Float16)v;
                hv[j] = hh;
                lv[j] = (_Float16)(v - (float)hh);
            }
            const int e = (kblk * 4 + mt) * 64 + (q * 16 + m);   // == ...*64 + lane
            Axh[e] = hv;
            Axl[e] = lv;
        }
    }
    __syncthreads();

    float q1d[16], q2d[16];
    int   q1i[16], q2i[16];
    #pragma unroll
    for (int i = 0; i < 16; ++i) { q1d[i] = 3.4e38f; q2d[i] = 3.4e38f; q1i[i] = 0; q2i[i] = 0; }

    // B-fragment prefetch slots (1-deep software pipeline)
    half8 nbh[2], nbl[2];
    #pragma unroll
    for (int nt = 0; nt < 2; ++nt) {
        const int ntile = wv * 16 + nt;
        const size_t be = ((size_t)(ntile * 8) * 64 + lane) * 8;
        nbh[nt] = *(const half8*)(cbFh + be);
        nbl[nt] = *(const half8*)(cbFl + be);
    }

    #pragma unroll 1
    for (int grp = 0; grp < 8; ++grp) {   // 2 n-tiles per group
        f32x4 acc[4][2];   // [mt][nt]
        #pragma unroll
        for (int mt = 0; mt < 4; ++mt) {
            acc[mt][0] = (f32x4){0.f, 0.f, 0.f, 0.f};
            acc[mt][1] = (f32x4){0.f, 0.f, 0.f, 0.f};
        }

        #pragma unroll 2
        for (int kblk = 0; kblk < 8; ++kblk) {
            // consume current slot
            const half8 cbh0 = nbh[0], cbh1 = nbh[1];
            const half8 cbl0 = nbl[0], cbl1 = nbl[1];
            // issue next-iteration loads (wraps harmlessly at the very end)
            {
                const int nk = (kblk + 1) & 7;
                const int ng = (grp + ((kblk + 1) >> 3)) & 7;
                #pragma unroll
                for (int nt = 0; nt < 2; ++nt) {
                    const int ntile = wv * 16 + ng * 2 + nt;
                    const size_t be = ((size_t)(ntile * 8 + nk) * 64 + lane) * 8;
                    nbh[nt] = *(const half8*)(cbFh + be);
                    nbl[nt] = *(const half8*)(cbFl + be);
                }
            }
            half8 ahf[4], alf[4];
            #pragma unroll
            for (int mt = 0; mt < 4; ++mt) {
                const int e = (kblk * 4 + mt) * 64 + lane;
                ahf[mt] = Axh[e];
                alf[mt] = Axl[e];
            }
            // 3 terms: xh*ch + xh*cl + xl*ch  (= x*c minus tiny xl*cl)
            #pragma unroll
            for (int mt = 0; mt < 4; ++mt) {
                acc[mt][0] = __builtin_amdgcn_mfma_f32_16x16x32_f16(ahf[mt], cbh0, acc[mt][0], 0, 0, 0);
                acc[mt][1] = __builtin_amdgcn_mfma_f32_16x16x32_f16(ahf[mt], cbh1, acc[mt][1], 0, 0, 0);
            }
            #pragma unroll
            for (int mt = 0; mt < 4; ++mt) {
                acc[mt][0] = __builtin_amdgcn_mfma_f32_16x16x32_f16(ahf[mt], cbl0, acc[mt][0], 0, 0, 0);
                acc[mt][1] = __builtin_amdgcn_mfma_f32_16x16x32_f16(ahf[mt], cbl1, acc[mt][1], 0, 0, 0);
            }
            #pragma unroll
            for (int mt = 0; mt < 4; ++mt) {
                acc[mt][0] = __builtin_amdgcn_mfma_f32_16x16x32_f16(alf[mt], cbh0, acc[mt][0], 0, 0, 0);
                acc[mt][1] = __builtin_amdgcn_mfma_f32_16x16x32_f16(alf[mt], cbh1, acc[mt][1], 0, 0, 0);
            }
        }

        // fold this group's 32 codes into per-row top-2 (with i2)
        #pragma unroll
        for (int nt = 0; nt < 2; ++nt) {
            const int code = (wv * 16 + grp * 2 + nt) * 16 + (lane & 15);
            const float c2v = c2[code];
            #pragma unroll
            for (int mt = 0; mt < 4; ++mt) {
                #pragma unroll
                for (int reg = 0; reg < 4; ++reg) {
                    const float d = fmaf(-2.f, acc[mt][nt][reg], c2v);
                    const int qi = mt * 4 + reg;
                    const bool b1 = d < q1d[qi];
                    const bool b2 = d < q2d[qi];
                    q2d[qi] = b1 ? q1d[qi] : (b2 ? d : q2d[qi]);
                    q2i[qi] = b1 ? q1i[qi] : (b2 ? code : q2i[qi]);
                    q1d[qi] = b1 ? d : q1d[qi];
                    q1i[qi] = b1 ? code : q1i[qi];
                }
            }
        }
    }

    // cross-lane top-2 merge over the 16 code-columns (lane&15)
    #pragma unroll
    for (int off = 1; off < 16; off <<= 1) {
        #pragma unroll
        for (int qi = 0; qi < 16; ++qi) {
            const float od1 = __shfl_xor(q1d[qi], off);
            const int   oi1 = __shfl_xor(q1i[qi], off);
            const float od2 = __shfl_xor(q2d[qi], off);
            const int   oi2 = __shfl_xor(q2i[qi], off);
            const bool ob = od1 < q1d[qi];
            const float ld = ob ? q1d[qi] : od1;   // loser of the two firsts
            const int   li = ob ? q1i[qi] : oi1;
            const bool o2 = od2 < q2d[qi];
            const float md = o2 ? od2 : q2d[qi];   // winner of the two seconds
            const int   mi = o2 ? oi2 : q2i[qi];
            const bool lb = ld < md;
            q2d[qi] = lb ? ld : md;
            q2i[qi] = lb ? li : mi;
            q1d[qi] = ob ? od1 : q1d[qi];
            q1i[qi] = ob ? oi1 : q1i[qi];
        }
    }
    if ((lane & 15) == 0) {
        #pragma unroll
        for (int qi = 0; qi < 16; ++qi) {
            const int mt = qi >> 2, reg = qi & 3;
            const int row = mt * 16 + (lane >> 4) * 4 + reg;
            q1ds[wv][row] = q1d[qi];
            q1is[wv][row] = q1i[qi];
            q2ds[wv][row] = q2d[qi];
            q2is[wv][row] = q2i[qi];
        }
    }
    __syncthreads();
    if (tid < 64) {
        float d1 = q1ds[0][tid]; int i1 = q1is[0][tid];
        float d2 = q2ds[0][tid]; int i2 = q2is[0][tid];
        #pragma unroll
        for (int v = 1; v < 4; ++v) {
            const float od1 = q1ds[v][tid]; const int oi1 = q1is[v][tid];
            const float od2 = q2ds[v][tid]; const int oi2 = q2is[v][tid];
            const bool ob = od1 < d1;
            const float ld = ob ? d1 : od1;
            const int   li = ob ? i1 : oi1;
            const bool o2 = od2 < d2;
            const float md = o2 ? od2 : d2;
            const int   mi = o2 ? oi2 : i2;
            const bool lb = ld < md;
            d2 = lb ? ld : md;
            i2 = lb ? li : mi;
            d1 = ob ? od1 : d1;
            i1 = ob ? oi1 : i1;
        }
        idx_s[tid] = i1;
        if (d2 - d1 < THR) {                 // tight gap -> exact top-2 rescore
            const int pos = atomicAdd(&nflag, 1);
            flg[pos] = tid | (i2 << 6);
        }
    }
    __syncthreads();

    // ---- Cheap exact rescore of flagged rows (expected ~0 per block).
    // Exact x reconstructed from LDS (xh+xl, err 2^-24); |x-c|^2 in fp32.
    const int nf = nflag;
    for (int fi = 0; fi < nf; ++fi) {
        if (wv == 0) {
            const int pack = flg[fi];
            const int w = pack & 63;
            const int i2 = pack >> 6;
            const int i1 = idx_s[w];
            const int mt = w >> 4, m = w & 15;
            float s1 = 0.f, s2 = 0.f;
            #pragma unroll
            for (int cc = 0; cc < 4; ++cc) {
                const int c = lane * 4 + cc;
                const int kblk = c >> 5, q = (c >> 3) & 3, j = c & 7;
                const int e = (kblk * 4 + mt) * 64 + q * 16 + m;
                const float xv = (float)Axh[e][j] + (float)Axl[e][j];
                const float e1 = cb[(size_t)i1 * Cd + c] - xv;
                const float e2 = cb[(size_t)i2 * Cd + c] - xv;
                s1 = fmaf(e1, e1, s1);
                s2 = fmaf(e2, e2, s2);
            }
            #pragma unroll
            for (int off = 32; off >= 1; off >>= 1) {
                s1 += __shfl_xor(s1, off);
                s2 += __shfl_xor(s2, off);
            }
            if (lane == 0 && (s2 < s1 || (s2 == s1 && i2 < i1))) idx_s[w] = i2;
        }
    }
    __syncthreads();

    // indices out (post-rescore)
    if (tid < 64) out[IDX_OFF + bh * 64 + tid] = (float)idx_s[tid];

    // ---- Fused epilogue: quant gather (L2-resident cb), coalesced writes,
    //      loss from LDS-reconstructed x (xh+xl, error ~2^-24).
    {
        const int w = tid & 63;           // row
        const int cq = wv;                // c-quarter: c in [cq*64, cq*64+64)
        const int m = w & 15, mt = w >> 4;
        const int myidx = idx_s[w];
        const float4* cbrow = (const float4*)(cb + (size_t)myidx * Cd + cq * 64);
        float lsum = 0.f;
        #pragma unroll
        for (int half = 0; half < 2; ++half) {
            const int kblk = cq * 2 + half;
            #pragma unroll
            for (int q = 0; q < 4; ++q) {
                const int e = (kblk * 4 + mt) * 64 + q * 16 + m;
                const half8 hv = Axh[e];
                const half8 lv = Axl[e];
                const float4 qa = cbrow[half * 8 + q * 2];
                const float4 qb = cbrow[half * 8 + q * 2 + 1];
                const float qv[8] = {qa.x, qa.y, qa.z, qa.w, qb.x, qb.y, qb.z, qb.w};
                const int cbase = cq * 64 + half * 32 + q * 8;
                #pragma unroll
                for (int j = 0; j < 8; ++j) {
                    const float xv = (float)hv[j] + (float)lv[j];
                    const float dd = qv[j] - xv;
                    lsum += dd * dd;
                    out[(((size_t)b * Cd + cbase + j) * Hn + h) * Wn + w] = qv[j];
                }
            }
        }
        #pragma unroll
        for (int off = 32; off >= 1; off >>= 1) lsum += __shfl_xor(lsum, off);
        if (lane == 0) red[wv] = lsum;
    }
    __syncthreads();
    if (tid == 0) {
        const float s = (red[0] + red[1] + red[2] + red[3]) * (1.0f / 16777216.0f);
        atomicAdd(out + LOSS_OFF, s);
        atomicAdd(out + LOSS_OFF + 1, s);
    }
}

// ---------------------------------------------------------------------------
extern "C" void kernel_launch(void* const* d_in, const int* in_sizes, int n_in,
                              void* d_out, int out_size, void* d_ws, size_t ws_size,
                              hipStream_t stream) {
    const float* x  = (const float*)d_in[0];   // (16,256,64,64)
    const float* cb = (const float*)d_in[1];   // (1024,256)
    float* out = (float*)d_out;
    char* ws = (char*)d_ws;
    _Float16* cbFh = (_Float16*)(ws + WS_CBFH);
    _Float16* cbFl = (_Float16*)(ws + WS_CBFL);
    float* c2      = (float*)(ws + WS_C2);

    prep<<<64, 256, 0, stream>>>(cb, cbFh, cbFl, c2, out);
    vq_main<<<Bn * Hn, 256, 0, stream>>>(x, cbFh, cbFl, c2, cb, out);
}

// Round 4
// 225.746 us; speedup vs baseline: 1.3769x; 1.0726x over previous
//
#include <hip/hip_runtime.h>

// Problem constants
constexpr int Bn = 16, Cd = 256, Hn = 64, Wn = 64, Kc = 1024;
constexpr int QUANT_ELEMS = Bn * Hn * Wn * Cd;   // 16777216
constexpr int LOSS_OFF = QUANT_ELEMS;            // +0 codebook_loss, +1 commitment_loss
constexpr int IDX_OFF = QUANT_ELEMS + 2;         // 65536 indices (stored as float)

typedef _Float16 half8 __attribute__((ext_vector_type(8)));
typedef float f32x4 __attribute__((ext_vector_type(4)));

// ws layout (bytes):
constexpr size_t WS_CBFH = 0;                    // 512 KB fp16 hi codebook (B-frag)
constexpr size_t WS_CBFL = 512 * 1024;           // 512 KB fp16 lo residual
constexpr size_t WS_C2   = 1024 * 1024;          // 4 KB

// Gap threshold for exact top-2 rescore (3-term error sigma ~1e-5).
constexpr float THR = 1e-4f;

// ---------------------------------------------------------------------------
// Prep: 64 blocks x 16 codes. Produces cbFh/cbFl (B-fragment fp16 hi/lo), c2,
// zeroes losses.
__global__ __launch_bounds__(256) void prep(const float* __restrict__ cb,
                                            _Float16* __restrict__ cbFh,
                                            _Float16* __restrict__ cbFl,
                                            float* __restrict__ c2,
                                            float* __restrict__ out) {
    __shared__ float cbs[16][257];   // 16 codes x 256 c, +1 pad
    const int tid = threadIdx.x;
    const int k0 = blockIdx.x * 16;  // 64 blocks
    {   // load tile, coalesced along c
        const int c4 = (tid & 63) * 4;
        const int r0 = tid >> 6;
        #pragma unroll
        for (int it = 0; it < 4; ++it) {
            const int r = r0 + it * 4;
            const float4 v = *(const float4*)&cb[(size_t)(k0 + r) * Cd + c4];
            cbs[r][c4] = v.x; cbs[r][c4 + 1] = v.y; cbs[r][c4 + 2] = v.z; cbs[r][c4 + 3] = v.w;
        }
    }
    __syncthreads();
    {   // c2: 16 threads per code
        const int i = tid >> 4, part = tid & 15;
        float s = 0.f;
        #pragma unroll
        for (int c = part * 16; c < part * 16 + 16; ++c) { const float v = cbs[i][c]; s += v * v; }
        s += __shfl_xor(s, 1);
        s += __shfl_xor(s, 2);
        s += __shfl_xor(s, 4);
        s += __shfl_xor(s, 8);
        if (part == 0) c2[k0 + i] = s;
    }
    // B frag (16x16x32 f16): lane l holds B[k=(l>>4)*8+j][n=l&15]
    for (int t = tid; t < 512; t += 256) {
        const int kblk = t >> 6;     // 0..7
        const int l = t & 63;
        const int code_l = l & 15;
        const int cbase = kblk * 32 + (l >> 4) * 8;
        half8 hv, lv;
        #pragma unroll
        for (int j = 0; j < 8; ++j) {
            const float v = cbs[code_l][cbase + j];
            const _Float16 hh = (_Float16)v;
            hv[j] = hh;
            lv[j] = (_Float16)(v - (float)hh);
        }
        const size_t e = (size_t)(blockIdx.x * 8 + kblk) * 64 + l;
        *(half8*)(cbFh + e * 8) = hv;
        *(half8*)(cbFl + e * 8) = lv;
    }
    if (blockIdx.x == 0 && tid == 0) {
        out[LOSS_OFF] = 0.f; out[LOSS_OFF + 1] = 0.f;
    }
}

// ---------------------------------------------------------------------------
// Main MFMA kernel v8. Block = one (b,h) = 64 rows x 256 c, 512 threads.
// Changes vs v7 (171 us, MfmaUtil 26, Occupancy 21.5 @ 2 waves/SIMD):
//  - 8 waves/block: wave = (mt_half 2 rows-of-32, nt_quarter 16 ntiles).
//    Per-wave live regs drop (q arrays 32, acc 16, A 16) -> fits 128-reg
//    budget -> __launch_bounds__(512,4) = 4 waves/SIMD, LDS 2 blocks/CU
//    -> 16 waves/CU = 50% occupancy (2x v7).
//  - Everything else (3-term MFMA, top-2 + cheap exact rescore, LDS-exact
//    epilogue) retained.
__global__ __launch_bounds__(512, 4) void vq_main(const float* __restrict__ x,
                                                  const _Float16* __restrict__ cbFh,
                                                  const _Float16* __restrict__ cbFl,
                                                  const float* __restrict__ c2,
                                                  const float* __restrict__ cb,
                                                  float* __restrict__ out) {
    __shared__ half8 Axh[2048];   // 32 KB: [kblk 8][mt 4][lane 64]
    __shared__ half8 Axl[2048];   // 32 KB
    __shared__ float q1ds[8][32];
    __shared__ int   q1is[8][32];
    __shared__ float q2ds[8][32];
    __shared__ int   q2is[8][32];
    __shared__ int   idx_s[64];
    __shared__ float red[8];
    __shared__ int   flg[64];     // packed: row | (i2 << 6)
    __shared__ int   nflag;

    const int tid = threadIdx.x;
    const int lane = tid & 63;
    const int wv = tid >> 6;          // 0..7
    const int mth = wv & 1;           // m-half: rows [mth*32, mth*32+32)
    const int ntq = wv >> 1;          // n-quarter: ntiles [ntq*16, ntq*16+16)
    const int bh = blockIdx.x;
    const int b = bh >> 6, h = bh & 63;

    if (tid == 0) nflag = 0;

    // ---- Stage x-tile once: gather + fp16 hi/lo split + lane-contiguous writes
    {
        const int m = tid & 15;           // row within m-tile
        const int q = (tid >> 4) & 3;     // k-quad
        const int mtg = (tid >> 6) & 3;   // m-tile
        const int kh = tid >> 8;          // kblk-half (0/1)
        const int w = mtg * 16 + m;
        const float* xb = x + ((size_t)b * Cd * Hn + h) * Wn + w;   // + c*4096
        #pragma unroll
        for (int kk = 0; kk < 4; ++kk) {
            const int kblk = kh * 4 + kk;
            half8 hv, lv;
            #pragma unroll
            for (int j = 0; j < 8; ++j) {
                const int c = kblk * 32 + q * 8 + j;
                const float v = xb[(size_t)c * (Hn * Wn)];
                const _Float16 hh = (_Float16)v;
                hv[j] = hh;
                lv[j] = (_Float16)(v - (float)hh);
            }
            const int e = (kblk * 4 + mtg) * 64 + (q * 16 + m);   // == ...*64 + lane
            Axh[e] = hv;
            Axl[e] = lv;
        }
    }
    __syncthreads();

    float q1d[8], q2d[8];
    int   q1i[8], q2i[8];
    #pragma unroll
    for (int i = 0; i < 8; ++i) { q1d[i] = 3.4e38f; q2d[i] = 3.4e38f; q1i[i] = 0; q2i[i] = 0; }

    // B-fragment prefetch slots (1-deep software pipeline)
    half8 nbh[2], nbl[2];
    #pragma unroll
    for (int nt = 0; nt < 2; ++nt) {
        const int ntile = ntq * 16 + nt;
        const size_t be = ((size_t)(ntile * 8) * 64 + lane) * 8;
        nbh[nt] = *(const half8*)(cbFh + be);
        nbl[nt] = *(const half8*)(cbFl + be);
    }

    #pragma unroll 1
    for (int grp = 0; grp < 8; ++grp) {   // 2 n-tiles per group
        f32x4 acc[2][2];   // [ml][nt]
        acc[0][0] = (f32x4){0.f, 0.f, 0.f, 0.f};
        acc[0][1] = (f32x4){0.f, 0.f, 0.f, 0.f};
        acc[1][0] = (f32x4){0.f, 0.f, 0.f, 0.f};
        acc[1][1] = (f32x4){0.f, 0.f, 0.f, 0.f};

        #pragma unroll 2
        for (int kblk = 0; kblk < 8; ++kblk) {
            // consume current slot
            const half8 cbh0 = nbh[0], cbh1 = nbh[1];
            const half8 cbl0 = nbl[0], cbl1 = nbl[1];
            // issue next-iteration loads (wraps harmlessly at the very end)
            {
                const int nk = (kblk + 1) & 7;
                const int ng = (grp + ((kblk + 1) >> 3)) & 7;
                #pragma unroll
                for (int nt = 0; nt < 2; ++nt) {
                    const int ntile = ntq * 16 + ng * 2 + nt;
                    const size_t be = ((size_t)(ntile * 8 + nk) * 64 + lane) * 8;
                    nbh[nt] = *(const half8*)(cbFh + be);
                    nbl[nt] = *(const half8*)(cbFl + be);
                }
            }
            half8 ahf[2], alf[2];
            #pragma unroll
            for (int ml = 0; ml < 2; ++ml) {
                const int e = (kblk * 4 + mth * 2 + ml) * 64 + lane;
                ahf[ml] = Axh[e];
                alf[ml] = Axl[e];
            }
            // 3 terms: xh*ch + xh*cl + xl*ch  (= x*c minus tiny xl*cl)
            #pragma unroll
            for (int ml = 0; ml < 2; ++ml) {
                acc[ml][0] = __builtin_amdgcn_mfma_f32_16x16x32_f16(ahf[ml], cbh0, acc[ml][0], 0, 0, 0);
                acc[ml][1] = __builtin_amdgcn_mfma_f32_16x16x32_f16(ahf[ml], cbh1, acc[ml][1], 0, 0, 0);
            }
            #pragma unroll
            for (int ml = 0; ml < 2; ++ml) {
                acc[ml][0] = __builtin_amdgcn_mfma_f32_16x16x32_f16(ahf[ml], cbl0, acc[ml][0], 0, 0, 0);
                acc[ml][1] = __builtin_amdgcn_mfma_f32_16x16x32_f16(ahf[ml], cbl1, acc[ml][1], 0, 0, 0);
            }
            #pragma unroll
            for (int ml = 0; ml < 2; ++ml) {
                acc[ml][0] = __builtin_amdgcn_mfma_f32_16x16x32_f16(alf[ml], cbh0, acc[ml][0], 0, 0, 0);
                acc[ml][1] = __builtin_amdgcn_mfma_f32_16x16x32_f16(alf[ml], cbh1, acc[ml][1], 0, 0, 0);
            }
        }

        // fold this group's 32 codes into per-row top-2 (with i2)
        #pragma unroll
        for (int nt = 0; nt < 2; ++nt) {
            const int code = (ntq * 16 + grp * 2 + nt) * 16 + (lane & 15);
            const float c2v = c2[code];
            #pragma unroll
            for (int ml = 0; ml < 2; ++ml) {
                #pragma unroll
                for (int reg = 0; reg < 4; ++reg) {
                    const float d = fmaf(-2.f, acc[ml][nt][reg], c2v);
                    const int qi = ml * 4 + reg;
                    const bool b1 = d < q1d[qi];
                    const bool b2 = d < q2d[qi];
                    q2d[qi] = b1 ? q1d[qi] : (b2 ? d : q2d[qi]);
                    q2i[qi] = b1 ? q1i[qi] : (b2 ? code : q2i[qi]);
                    q1d[qi] = b1 ? d : q1d[qi];
                    q1i[qi] = b1 ? code : q1i[qi];
                }
            }
        }
    }

    // cross-lane top-2 merge over the 16 code-columns (lane&15)
    #pragma unroll
    for (int off = 1; off < 16; off <<= 1) {
        #pragma unroll
        for (int qi = 0; qi < 8; ++qi) {
            const float od1 = __shfl_xor(q1d[qi], off);
            const int   oi1 = __shfl_xor(q1i[qi], off);
            const float od2 = __shfl_xor(q2d[qi], off);
            const int   oi2 = __shfl_xor(q2i[qi], off);
            const bool ob = od1 < q1d[qi];
            const float ld = ob ? q1d[qi] : od1;   // loser of the two firsts
            const int   li = ob ? q1i[qi] : oi1;
            const bool o2 = od2 < q2d[qi];
            const float md = o2 ? od2 : q2d[qi];   // winner of the two seconds
            const int   mi = o2 ? oi2 : q2i[qi];
            const bool lb = ld < md;
            q2d[qi] = lb ? ld : md;
            q2i[qi] = lb ? li : mi;
            q1d[qi] = ob ? od1 : q1d[qi];
            q1i[qi] = ob ? oi1 : q1i[qi];
        }
    }
    if ((lane & 15) == 0) {
        #pragma unroll
        for (int qi = 0; qi < 8; ++qi) {
            const int ml = qi >> 2, reg = qi & 3;
            const int rl = ml * 16 + (lane >> 4) * 4 + reg;   // row within half (0..31)
            q1ds[wv][rl] = q1d[qi];
            q1is[wv][rl] = q1i[qi];
            q2ds[wv][rl] = q2d[qi];
            q2is[wv][rl] = q2i[qi];
        }
    }
    __syncthreads();
    if (tid < 64) {
        // row tid: half h covered by waves {h, h+2, h+4, h+6} (code-ascending)
        const int hh = tid >> 5, rl = tid & 31;
        float d1 = q1ds[hh][rl]; int i1 = q1is[hh][rl];
        float d2 = q2ds[hh][rl]; int i2 = q2is[hh][rl];
        #pragma unroll
        for (int v = 1; v < 4; ++v) {
            const int w2 = hh + 2 * v;
            const float od1 = q1ds[w2][rl]; const int oi1 = q1is[w2][rl];
            const float od2 = q2ds[w2][rl]; const int oi2 = q2is[w2][rl];
            const bool ob = od1 < d1;
            const float ld = ob ? d1 : od1;
            const int   li = ob ? i1 : oi1;
            const bool o2 = od2 < d2;
            const float md = o2 ? od2 : d2;
            const int   mi = o2 ? oi2 : i2;
            const bool lb = ld < md;
            d2 = lb ? ld : md;
            i2 = lb ? li : mi;
            d1 = ob ? od1 : d1;
            i1 = ob ? oi1 : i1;
        }
        idx_s[tid] = i1;
        if (d2 - d1 < THR) {                 // tight gap -> exact top-2 rescore
            const int pos = atomicAdd(&nflag, 1);
            flg[pos] = tid | (i2 << 6);
        }
    }
    __syncthreads();

    // ---- Cheap exact rescore of flagged rows (expected ~0 per block).
    // Exact x reconstructed from LDS (xh+xl, err 2^-24); |x-c|^2 in fp32.
    const int nf = nflag;
    for (int fi = 0; fi < nf; ++fi) {
        if (wv == 0) {
            const int pack = flg[fi];
            const int w = pack & 63;
            const int i2 = pack >> 6;
            const int i1 = idx_s[w];
            const int mt = w >> 4, m = w & 15;
            const _Float16* axh = (const _Float16*)Axh;
            const _Float16* axl = (const _Float16*)Axl;
            float s1 = 0.f, s2 = 0.f;
            #pragma unroll
            for (int cc = 0; cc < 4; ++cc) {
                const int c = lane * 4 + cc;
                const int kblk = c >> 5, q = (c >> 3) & 3, j = c & 7;
                const int e8 = ((kblk * 4 + mt) * 64 + q * 16 + m) * 8 + j;
                const float xv = (float)axh[e8] + (float)axl[e8];
                const float e1 = cb[(size_t)i1 * Cd + c] - xv;
                const float e2 = cb[(size_t)i2 * Cd + c] - xv;
                s1 = fmaf(e1, e1, s1);
                s2 = fmaf(e2, e2, s2);
            }
            #pragma unroll
            for (int off = 32; off >= 1; off >>= 1) {
                s1 += __shfl_xor(s1, off);
                s2 += __shfl_xor(s2, off);
            }
            if (lane == 0 && (s2 < s1 || (s2 == s1 && i2 < i1))) idx_s[w] = i2;
        }
    }
    __syncthreads();

    // indices out (post-rescore)
    if (tid < 64) out[IDX_OFF + bh * 64 + tid] = (float)idx_s[tid];

    // ---- Fused epilogue: quant gather (L2-resident cb), coalesced writes,
    //      loss from LDS-reconstructed x (xh+xl, error ~2^-24).
    {
        const int w = tid & 63;           // row
        const int kblk = wv;              // c-eighth: c in [wv*32, wv*32+32)
        const int m = w & 15, mt = w >> 4;
        const int myidx = idx_s[w];
        const float4* cbrow = (const float4*)(cb + (size_t)myidx * Cd + kblk * 32);
        float lsum = 0.f;
        #pragma unroll
        for (int q = 0; q < 4; ++q) {
            const int e = (kblk * 4 + mt) * 64 + q * 16 + m;
            const half8 hv = Axh[e];
            const half8 lv = Axl[e];
            const float4 qa = cbrow[q * 2];
            const float4 qb = cbrow[q * 2 + 1];
            const float qv[8] = {qa.x, qa.y, qa.z, qa.w, qb.x, qb.y, qb.z, qb.w};
            const int cbase = kblk * 32 + q * 8;
            #pragma unroll
            for (int j = 0; j < 8; ++j) {
                const float xv = (float)hv[j] + (float)lv[j];
                const float dd = qv[j] - xv;
                lsum += dd * dd;
                out[(((size_t)b * Cd + cbase + j) * Hn + h) * Wn + w] = qv[j];
            }
        }
        #pragma unroll
        for (int off = 32; off >= 1; off >>= 1) lsum += __shfl_xor(lsum, off);
        if (lane == 0) red[wv] = lsum;
    }
    __syncthreads();
    if (tid == 0) {
        float s = 0.f;
        #pragma unroll
        for (int i = 0; i < 8; ++i) s += red[i];
        s *= (1.0f / 16777216.0f);
        atomicAdd(out + LOSS_OFF, s);
        atomicAdd(out + LOSS_OFF + 1, s);
    }
}

// ---------------------------------------------------------------------------
extern "C" void kernel_launch(void* const* d_in, const int* in_sizes, int n_in,
                              void* d_out, int out_size, void* d_ws, size_t ws_size,
                              hipStream_t stream) {
    const float* x  = (const float*)d_in[0];   // (16,256,64,64)
    const float* cb = (const float*)d_in[1];   // (1024,256)
    float* out = (float*)d_out;
    char* ws = (char*)d_ws;
    _Float16* cbFh = (_Float16*)(ws + WS_CBFH);
    _Float16* cbFl = (_Float16*)(ws + WS_CBFL);
    float* c2      = (float*)(ws + WS_C2);

    prep<<<64, 256, 0, stream>>>(cb, cbFh, cbFl, c2, out);
    vq_main<<<Bn * Hn, 512, 0, stream>>>(x, cbFh, cbFl, c2, cb, out);
}